// Round 9
// baseline (1340.759 us; speedup 1.0000x reference)
//
#include <hip/hip_runtime.h>

typedef __attribute__((ext_vector_type(8))) short short8;
typedef __attribute__((ext_vector_type(4))) float float4v;

__device__ __forceinline__ float bf(unsigned short u) {
    return __uint_as_float(((unsigned int)u) << 16);
}
__device__ __forceinline__ unsigned short f2b(float f) {
    unsigned int u = __float_as_uint(f);
    unsigned int r = (u + 0x7FFFu + ((u >> 16) & 1u)) >> 16;
    return (unsigned short)r;
}

__constant__ float c_anchors[10] = {2.f,4.f,5.f,6.f,8.f,9.f,10.f,12.f,14.f,16.f};

// ============ W repack: fp32 [CO][CI][TAPS] -> bf16 hi/lo Wr[((co*TAPS+t)*2+p)*CI+ci] ============
__global__ __launch_bounds__(256) void repackW_kernel(const float* __restrict__ W,
                                                      unsigned short* __restrict__ Wr,
                                                      int CO, int CI, int TAPS) {
    int i = blockIdx.x * 256 + threadIdx.x;
    int n = CO * CI * TAPS;
    if (i >= n) return;
    int cit = CI * TAPS;
    int co = i / cit;
    int rem = i - co * cit;
    int ci = rem / TAPS;
    int t = rem - ci * TAPS;
    float v = W[i];
    unsigned short h = f2b(v);
    unsigned short l = f2b(v - bf(h));
    size_t o = ((size_t)(co * TAPS + t) * 2) * CI + ci;
    Wr[o] = h;
    Wr[o + CI] = l;
}

// ============ Xt helpers: transposed bf16 hi/lo slab, planes h/l ============
__global__ __launch_bounds__(256) void zeroXt_kernel(unsigned short* __restrict__ Xt, int CI) {
    int i = blockIdx.x * 256 + threadIdx.x;
    if (i < 2 * CI) {
        int row = (i >= CI) ? 769 : 0;
        int co = (i >= CI) ? (i - CI) : i;
        Xt[(size_t)row * CI + co] = 0;
        Xt[(size_t)770 * CI + (size_t)row * CI + co] = 0;
    }
}

// src fp32 [CI][768] -> Xt rows 1..768 (row l+1 = X[:,l]), hi/lo planes
__global__ __launch_bounds__(256) void decomp_kernel(const float* __restrict__ src,
                                                     unsigned short* __restrict__ Xt, int CI) {
    __shared__ float T[32][33];
    int l0 = blockIdx.x * 32, ci0 = blockIdx.y * 32;
    int tid = threadIdx.x;
#pragma unroll
    for (int i = 0; i < 4; i++) {
        int slot = tid + 256 * i;
        int r = slot >> 5, c = slot & 31;
        T[r][c] = src[(size_t)(ci0 + r) * 768 + l0 + c];
    }
    __syncthreads();
    unsigned short* Xh = Xt;
    unsigned short* Xl = Xt + (size_t)770 * CI;
#pragma unroll
    for (int i = 0; i < 4; i++) {
        int slot = tid + 256 * i;
        int li = slot >> 5, cc = slot & 31;
        float v = T[cc][li];
        unsigned short h = f2b(v);
        float lo = v - bf(h);
        size_t o = (size_t)(l0 + li + 1) * CI + ci0 + cc;
        Xh[o] = h;
        Xl[o] = f2b(lo);
    }
}

// ============ repacked-W MFMA conv-as-GEMM: A direct-from-global, Bt LDS only ============
// SEGM=0: slab row of col c = c+1; SEGM=1: row = (c/7)*9 + c%7 + 1
template <int TAPS, int SEGM>
__global__ __launch_bounds__(512, 6) void convmmW_kernel(const unsigned short* __restrict__ Wr,
                                                         const unsigned short* __restrict__ Xt,
                                                         float* __restrict__ G,
                                                         int CO, int CI, int S, int NCOL, int planeElems) {
    constexpr int BROWS = SEGM ? 168 : 130;
    __shared__ unsigned short Bt[2][BROWS * 40];
    int tid = threadIdx.x;
    int lane = tid & 63, wid = tid >> 6;
    int q = lane >> 4, ln = lane & 15;
    int co0 = blockIdx.x * 64;
    int c0 = blockIdx.y * 128;
    int s = blockIdx.z;
    int kPer = CI / S, cis = s * kPer;
    const unsigned short* Xh = Xt;
    const unsigned short* Xl = Xt + planeElems;
    int row0 = SEGM ? ((c0 / 7) * 9 + c0 % 7) : c0;

    float4v zero4 = {0.f, 0.f, 0.f, 0.f};
    float4v acc[2][2];
    acc[0][0] = zero4; acc[0][1] = zero4; acc[1][0] = zero4; acc[1][1] = zero4;

    int wave_m = (wid >> 2) * 32;
    int wave_n = (wid & 3) * 32;

    size_t wbase[2];
#pragma unroll
    for (int mf = 0; mf < 2; mf++) {
        int row = co0 + wave_m + mf * 16 + ln;
        wbase[mf] = ((size_t)row * TAPS) * 2 * CI + q * 8;
    }
    int rowb[2];
#pragma unroll
    for (int nf = 0; nf < 2; nf++) {
        int col = c0 + wave_n + nf * 16 + ln;
        rowb[nf] = SEGM ? ((col / 7) * 9 + col % 7 - row0) : (wave_n + nf * 16 + ln);
    }

    for (int kb = 0; kb < kPer; kb += 32) {
        int cib = cis + kb;
        // stage B slab: BROWS rows, 32 ci, both planes, 16B chunks
#pragma unroll
        for (int i = 0; i < 3; i++) {
            int slot = tid + 512 * i;
            if (slot < BROWS * 8) {
                int p = slot >= BROWS * 4 ? 1 : 0;
                int rem = slot - p * BROWS * 4;
                int r = rem >> 2, qq = rem & 3;
                const unsigned short* src = (p ? Xl : Xh) + (size_t)(row0 + r) * CI + cib + qq * 8;
                short8 v = *(const short8*)src;
                *(short8*)&Bt[p][r * 40 + qq * 8] = v;
            }
        }
        __syncthreads();
#pragma unroll
        for (int t = 0; t < TAPS; t++) {
            int shift = (TAPS == 1) ? 1 : t;
            // A fragments direct from global (repacked layout, 16B/lane contiguous)
            short8 ah[2], al[2];
#pragma unroll
            for (int mf = 0; mf < 2; mf++) {
                const unsigned short* pa = Wr + wbase[mf] + (size_t)(t * 2) * CI + cib;
                ah[mf] = *(const short8*)pa;
                al[mf] = *(const short8*)(pa + CI);
            }
            short8 bh[2], bl[2];
#pragma unroll
            for (int nf = 0; nf < 2; nf++) {
                int rrow = rowb[nf] + shift;
                bh[nf] = *(const short8*)&Bt[0][rrow * 40 + q * 8];
                bl[nf] = *(const short8*)&Bt[1][rrow * 40 + q * 8];
            }
#pragma unroll
            for (int mf = 0; mf < 2; mf++)
#pragma unroll
                for (int nf = 0; nf < 2; nf++) {
                    acc[mf][nf] = __builtin_amdgcn_mfma_f32_16x16x32_bf16(ah[mf], bh[nf], acc[mf][nf], 0, 0, 0);
                    acc[mf][nf] = __builtin_amdgcn_mfma_f32_16x16x32_bf16(ah[mf], bl[nf], acc[mf][nf], 0, 0, 0);
                    acc[mf][nf] = __builtin_amdgcn_mfma_f32_16x16x32_bf16(al[mf], bh[nf], acc[mf][nf], 0, 0, 0);
                }
        }
        __syncthreads();
    }
    float* Gz = G + (size_t)s * CO * NCOL;
#pragma unroll
    for (int mf = 0; mf < 2; mf++)
#pragma unroll
        for (int nf = 0; nf < 2; nf++) {
            int col = c0 + wave_n + nf * 16 + ln;
            int rowb2 = co0 + wave_m + mf * 16 + q * 4;
#pragma unroll
            for (int r = 0; r < 4; r++)
                Gz[(size_t)(rowb2 + r) * NCOL + col] = acc[mf][nf][r];
        }
}

// ============ legacy in-kernel-decompose conv (fallback for big convs if ws too small) ============
__global__ __launch_bounds__(512, 6) void convmm_kernel(const float* __restrict__ W,
                                                        const unsigned short* __restrict__ Xt,
                                                        float* __restrict__ G,
                                                        int CO, int CI, int S, int NCOL, int planeElems) {
    constexpr int RS = 3 * 32 + 8;
    __shared__ unsigned short At[2][64 * RS];
    __shared__ unsigned short Bt[2][130 * 40];
    int tid = threadIdx.x;
    int lane = tid & 63, wid = tid >> 6;
    int q = lane >> 4, ln = lane & 15;
    int co0 = blockIdx.x * 64;
    int c0 = blockIdx.y * 128;
    int s = blockIdx.z;
    int kPer = CI / S, cis = s * kPer;
    const unsigned short* Xh = Xt;
    const unsigned short* Xl = Xt + planeElems;

    float4v zero4 = {0.f, 0.f, 0.f, 0.f};
    float4v acc[2][2];
    acc[0][0] = zero4; acc[0][1] = zero4; acc[1][0] = zero4; acc[1][1] = zero4;

    int wave_m = (wid >> 2) * 32;
    int wave_n = (wid & 3) * 32;

    for (int kb = 0; kb < kPer; kb += 32) {
        int cib = cis + kb;
#pragma unroll
        for (int i = 0; i < 2; i++) {
            int slot = tid + 512 * i;
            int row = slot >> 4, cc0 = (slot & 15) * 2;
            const float* wp = W + ((size_t)(co0 + row) * CI + cib + cc0) * 3;
            float fa[6];
#pragma unroll
            for (int j = 0; j < 6; j++) fa[j] = wp[j];
#pragma unroll
            for (int t = 0; t < 3; t++) {
                unsigned short h0 = f2b(fa[t]);
                unsigned short h1 = f2b(fa[t + 3]);
                unsigned short e0 = f2b(fa[t] - bf(h0));
                unsigned short e1 = f2b(fa[t + 3] - bf(h1));
                *(unsigned int*)&At[0][row * RS + t * 32 + cc0] =
                    (unsigned int)h0 | ((unsigned int)h1 << 16);
                *(unsigned int*)&At[1][row * RS + t * 32 + cc0] =
                    (unsigned int)e0 | ((unsigned int)e1 << 16);
            }
        }
#pragma unroll
        for (int i = 0; i < 3; i++) {
            int slot = tid + 512 * i;
            if (slot < 1040) {
                int p = slot >= 520 ? 1 : 0;
                int rem = slot - p * 520;
                int r = rem >> 2, qq = rem & 3;
                const unsigned short* src = (p ? Xl : Xh) + (size_t)(c0 + r) * CI + cib + qq * 8;
                short8 v = *(const short8*)src;
                *(short8*)&Bt[p][r * 40 + qq * 8] = v;
            }
        }
        __syncthreads();
#pragma unroll
        for (int t = 0; t < 3; t++) {
            short8 bh[2], bl[2];
#pragma unroll
            for (int nf = 0; nf < 2; nf++) {
                int rrow = wave_n + nf * 16 + ln + t;
                bh[nf] = *(const short8*)&Bt[0][rrow * 40 + q * 8];
                bl[nf] = *(const short8*)&Bt[1][rrow * 40 + q * 8];
            }
#pragma unroll
            for (int mf = 0; mf < 2; mf++) {
                int mrow = wave_m + mf * 16 + ln;
                short8 ah = *(const short8*)&At[0][mrow * RS + t * 32 + q * 8];
                short8 al = *(const short8*)&At[1][mrow * RS + t * 32 + q * 8];
#pragma unroll
                for (int nf = 0; nf < 2; nf++) {
                    acc[mf][nf] = __builtin_amdgcn_mfma_f32_16x16x32_bf16(ah, bh[nf], acc[mf][nf], 0, 0, 0);
                    acc[mf][nf] = __builtin_amdgcn_mfma_f32_16x16x32_bf16(ah, bl[nf], acc[mf][nf], 0, 0, 0);
                    acc[mf][nf] = __builtin_amdgcn_mfma_f32_16x16x32_bf16(al, bh[nf], acc[mf][nf], 0, 0, 0);
                }
            }
        }
        __syncthreads();
    }
    float* Gz = G + (size_t)s * CO * NCOL;
#pragma unroll
    for (int mf = 0; mf < 2; mf++)
#pragma unroll
        for (int nf = 0; nf < 2; nf++) {
            int col = c0 + wave_n + nf * 16 + ln;
            int rowb2 = co0 + wave_m + mf * 16 + q * 4;
#pragma unroll
            for (int r = 0; r < 4; r++)
                Gz[(size_t)(rowb2 + r) * NCOL + col] = acc[mf][nf][r];
        }
}

// finalize: sum P planes + bias -> transposed bf16 hi/lo Xt (770-row slab)
__global__ __launch_bounds__(256) void finsum_x_kernel(const float* __restrict__ G,
                                                       const float* __restrict__ bias,
                                                       unsigned short* __restrict__ Xt,
                                                       int CO, int P) {
    __shared__ float T[64][65];
    int co0 = blockIdx.x * 64, l0 = blockIdx.y * 64;
    int tid = threadIdx.x;
#pragma unroll 1
    for (int i = 0; i < 16; i++) {
        int slot = tid + 256 * i;
        int r = slot >> 6, c = slot & 63;
        float v = bias[co0 + r];
        for (int p = 0; p < P; p++) v += G[((size_t)p * CO + co0 + r) * 768 + l0 + c];
        T[r][c] = v;
    }
    __syncthreads();
    unsigned short* Xh = Xt;
    unsigned short* Xl = Xt + (size_t)770 * CO;
#pragma unroll 1
    for (int i = 0; i < 16; i++) {
        int slot = tid + 256 * i;
        int li = slot >> 6, ci = slot & 63;
        float v = T[ci][li];
        unsigned short h = f2b(v);
        float lo = v - bf(h);
        size_t o = (size_t)(l0 + li + 1) * CO + co0 + ci;
        Xh[o] = h;
        Xl[o] = f2b(lo);
    }
}

// finalize: sum P planes + bias -> 770-slab AND fp32 [CO][768]
__global__ __launch_bounds__(256) void finsum_xf_kernel(const float* __restrict__ G,
                                                        const float* __restrict__ bias,
                                                        unsigned short* __restrict__ Xt,
                                                        float* __restrict__ outF,
                                                        int CO, int P) {
    __shared__ float T[64][65];
    int co0 = blockIdx.x * 64, l0 = blockIdx.y * 64;
    int tid = threadIdx.x;
#pragma unroll 1
    for (int i = 0; i < 16; i++) {
        int slot = tid + 256 * i;
        int r = slot >> 6, c = slot & 63;
        float v = bias[co0 + r];
        for (int p = 0; p < P; p++) v += G[((size_t)p * CO + co0 + r) * 768 + l0 + c];
        T[r][c] = v;
        outF[(size_t)(co0 + r) * 768 + l0 + c] = v;
    }
    __syncthreads();
    unsigned short* Xh = Xt;
    unsigned short* Xl = Xt + (size_t)770 * CO;
#pragma unroll 1
    for (int i = 0; i < 16; i++) {
        int slot = tid + 256 * i;
        int li = slot >> 6, ci = slot & 63;
        float v = T[ci][li];
        unsigned short h = f2b(v);
        float lo = v - bf(h);
        size_t o = (size_t)(l0 + li + 1) * CO + co0 + ci;
        Xh[o] = h;
        Xl[o] = f2b(lo);
    }
}

// finalize: sum P planes + bias -> segmented slab [1160][512] hi/lo (+relu)
__global__ __launch_bounds__(256) void finsum_seg_kernel(const float* __restrict__ G,
                                                         const float* __restrict__ bias,
                                                         unsigned short* __restrict__ Xs,
                                                         int P, int relu) {
    __shared__ float T[64][65];
    int co0 = blockIdx.x * 64, c0 = blockIdx.y * 64;
    int tid = threadIdx.x;
#pragma unroll 1
    for (int i = 0; i < 16; i++) {
        int slot = tid + 256 * i;
        int r = slot >> 6, c = slot & 63;
        float v = bias[co0 + r];
        for (int p = 0; p < P; p++) v += G[((size_t)p * 512 + co0 + r) * 896 + c0 + c];
        if (relu) v = fmaxf(v, 0.f);
        T[r][c] = v;
    }
    __syncthreads();
    unsigned short* Xh = Xs;
    unsigned short* Xl = Xs + (size_t)1160 * 512;
#pragma unroll 1
    for (int i = 0; i < 16; i++) {
        int slot = tid + 256 * i;
        int li = slot >> 6, ci = slot & 63;
        float v = T[ci][li];
        int c = c0 + li;
        int row = (c / 7) * 9 + c % 7 + 1;
        unsigned short h = f2b(v);
        float lo = v - bf(h);
        size_t o = (size_t)row * 512 + co0 + ci;
        Xh[o] = h;
        Xl[o] = f2b(lo);
    }
}

// finalize: sum P planes + bias (+relu) -> fp32 [CO][ncol]
__global__ __launch_bounds__(256) void finsum_f_kernel(const float* __restrict__ G,
                                                       const float* __restrict__ bias,
                                                       float* __restrict__ out,
                                                       int CO, int P, int ncol, int relu) {
    int i = blockIdx.x * 256 + threadIdx.x;
    if (i >= CO * ncol) return;
    int r = i / ncol, c = i - r * ncol;
    float v = bias[r];
    for (int p = 0; p < P; p++) v += G[((size_t)p * CO + r) * ncol + c];
    if (relu) v = fmaxf(v, 0.f);
    out[i] = v;
}

// ---------------- finalize for fp32 split-K gemm path ----------------
__global__ __launch_bounds__(256) void finalize_kernel(const float* __restrict__ part,
                                                       float* __restrict__ out,
                                                       const float* __restrict__ bias,
                                                       int RPAD, int R, int NCOLS, int S, int relu) {
    int i = blockIdx.x * 256 + threadIdx.x;
    int total = R * NCOLS;
    if (i >= total) return;
    int r = i / NCOLS;
    int c = i - r * NCOLS;
    float v = 0.f;
    for (int s = 0; s < S; s++) v += part[((size_t)s * RPAD + r) * NCOLS + c];
    v += bias[r];
    if (relu) v = fmaxf(v, 0.f);
    out[i] = v;
}

// ---------------- fp32 gather-GEMM (heads, fc1-3, output heads) ----------------
template <int MODE, int EPI>
__global__ __launch_bounds__(256) void gemm_kernel(const float* __restrict__ W,
                                                   const float* __restrict__ B,
                                                   const float* __restrict__ bias,
                                                   float* __restrict__ outF,
                                                   int R, int K, int NCOLS, int LDB, int S, int relu) {
    __shared__ __align__(16) float Bt[16][68];
    __shared__ __align__(16) float Wt[16][68];
    int tid = threadIdx.x;
    int tx = tid & 15, ty = tid >> 4;
    int r0 = blockIdx.x * 64, c0 = blockIdx.y * 64, s = blockIdx.z;
    int kPer = K / S;
    int k0s = s * kPer;
    float acc[4][4] = {};
    for (int kb = 0; kb < kPer; kb += 16) {
        int k0 = k0s + kb;
        {
            int rr = r0 + (tid >> 2);
            int q = tid & 3;
            float4 wv4 = {0.f, 0.f, 0.f, 0.f};
            if (rr < R) wv4 = *(const float4*)(W + (size_t)rr * K + k0 + q * 4);
            Wt[q * 4 + 0][tid >> 2] = wv4.x;
            Wt[q * 4 + 1][tid >> 2] = wv4.y;
            Wt[q * 4 + 2][tid >> 2] = wv4.z;
            Wt[q * 4 + 3][tid >> 2] = wv4.w;
        }
#pragma unroll
        for (int p = 0; p < 4; p++) {
            int kk = p * 4 + (tid >> 6);
            int c = tid & 63;
            int k = k0 + kk;
            int col = c0 + c;
            float v;
            if (MODE == 0) {
                v = B[(size_t)k * LDB + col];
            } else {
                int co = k / 7;
                int b7 = k - co * 7;
                v = B[(size_t)co * 896 + col * 7 + b7];
            }
            Bt[kk][c] = v;
        }
        __syncthreads();
#pragma unroll
        for (int kk = 0; kk < 16; kk++) {
            float4 bv = *(const float4*)&Bt[kk][tx * 4];
            float4 wv = *(const float4*)&Wt[kk][ty * 4];
            float bb[4] = {bv.x, bv.y, bv.z, bv.w};
            float ww[4] = {wv.x, wv.y, wv.z, wv.w};
#pragma unroll
            for (int i = 0; i < 4; i++)
#pragma unroll
                for (int j = 0; j < 4; j++)
                    acc[i][j] = fmaf(ww[i], bb[j], acc[i][j]);
        }
        __syncthreads();
    }
    if (EPI == 0) {
        if (S > 1) {
#pragma unroll
            for (int i = 0; i < 4; i++) {
                int r = r0 + ty * 4 + i;
                if (r < R) {
                    float4 o = {acc[i][0], acc[i][1], acc[i][2], acc[i][3]};
                    *(float4*)&outF[((size_t)s * R + r) * NCOLS + c0 + tx * 4] = o;
                }
            }
        } else {
#pragma unroll
            for (int i = 0; i < 4; i++) {
                int r = r0 + ty * 4 + i;
                if (r < R) {
                    float bv = bias[r];
#pragma unroll
                    for (int j = 0; j < 4; j++) {
                        float v = acc[i][j] + bv;
                        if (relu) v = fmaxf(v, 0.f);
                        outF[(size_t)r * NCOLS + c0 + tx * 4 + j] = v;
                    }
                }
            }
        }
    } else {
#pragma unroll
        for (int i = 0; i < 4; i++) {
            int r = r0 + ty * 4 + i;
            if (r < R) {
                float bv = bias[r];
#pragma unroll
                for (int j = 0; j < 4; j++) {
                    int col = c0 + tx * 4 + j;
                    float v = acc[i][j] + bv;
                    if (EPI == 1) outF[512 + col * 21 + r] = v;
                    else outF[3200 + col * 40 + r] = v;
                }
            }
        }
    }
}

// ---------------- proposals: softmax, anchor decode ----------------
__global__ __launch_bounds__(256) void proposal_kernel(const float* __restrict__ clsS,
                                                       const float* __restrict__ segS,
                                                       float* __restrict__ cls2, float* __restrict__ off2,
                                                       float* __restrict__ scores,
                                                       float* __restrict__ sArr, float* __restrict__ eArr) {
    int i = blockIdx.x * 256 + threadIdx.x;
    if (i >= 7680) return;
    int l = i / 10;
    int a = i - l * 10;
    float c0 = clsS[(a * 2 + 0) * 768 + l];
    float c1 = clsS[(a * 2 + 1) * 768 + l];
    cls2[i * 2] = c0;
    cls2[i * 2 + 1] = c1;
    float m = fmaxf(c0, c1);
    float e0 = expf(c0 - m), e1 = expf(c1 - m);
    scores[i] = e1 / (e0 + e1);
    float o0 = segS[(a * 2 + 0) * 768 + l];
    float o1 = segS[(a * 2 + 1) * 768 + l];
    off2[i * 2] = o0;
    off2[i * 2 + 1] = o1;
    float ah = c_anchors[a] * 0.5f;
    float ac = (float)l + 0.5f;
    float c = ac + o0 * (2.f * ah);
    float hl = ah * expf(o1);
    sArr[i] = fminf(fmaxf(c - hl, 0.f), 768.f);
    eArr[i] = fminf(fmaxf(c + hl, 0.f), 768.f);
}

// ---------------- bitonic top-k phase A ----------------
__global__ __launch_bounds__(1024) void sortA_kernel(const float* __restrict__ scores,
                                                     unsigned long long* __restrict__ runs) {
    __shared__ unsigned long long kk[1024];
    int tid = threadIdx.x;
    int gbase = blockIdx.x * 1024;
    int gi = gbase + tid;
    unsigned long long key = 0ull;
    if (gi < 7680) {
        unsigned int sb = __float_as_uint(scores[gi]);
        key = ((unsigned long long)sb << 32) | (unsigned long long)(0xFFFFFFFFu - (unsigned)gi);
    }
    kk[tid] = key;
    __syncthreads();
    for (int k = 2; k <= 1024; k <<= 1) {
        for (int j = k >> 1; j > 0; j >>= 1) {
            int ixj = tid ^ j;
            if (ixj > tid) {
                unsigned long long a = kk[tid], b = kk[ixj];
                bool descend = ((tid & k) == 0);
                if (descend ? (a < b) : (a > b)) { kk[tid] = b; kk[ixj] = a; }
            }
            __syncthreads();
        }
    }
    runs[gbase + tid] = kk[tid];
}

// ---------------- phase B: tree-merge, exact top-1024 desc ----------------
__global__ __launch_bounds__(1024) void sortB_kernel(const unsigned long long* __restrict__ runs,
                                                     const float* __restrict__ sArr, const float* __restrict__ eArr,
                                                     int* __restrict__ topI,
                                                     float* __restrict__ ss, float* __restrict__ ee) {
    __shared__ unsigned long long S[8192];
    int tid = threadIdx.x;
#pragma unroll
    for (int m = 0; m < 8; m++) S[m * 1024 + tid] = runs[m * 1024 + tid];
    __syncthreads();
#pragma unroll 1
    for (int level = 0; level < 3; level++) {
        int span = 1024 << level;
        int nm = 4 >> level;
        for (int m = 0; m < nm; m++) {
            int baseA = m * (span * 2);
            int baseB = baseA + span;
            unsigned long long a = S[baseA + tid], b = S[baseB + 1023 - tid];
            S[baseA + tid] = (a > b) ? a : b;
        }
        __syncthreads();
        for (int j = 512; j > 0; j >>= 1) {
            for (int m = 0; m < nm; m++) {
                int baseA = m * (span * 2);
                int ixj = tid ^ j;
                if (ixj > tid) {
                    unsigned long long a = S[baseA + tid], b = S[baseA + ixj];
                    if (a < b) { S[baseA + tid] = b; S[baseA + ixj] = a; }
                }
            }
            __syncthreads();
        }
    }
    int idx = (int)(0xFFFFFFFFu - (unsigned int)(S[tid] & 0xFFFFFFFFull));
    topI[tid] = idx;
    ss[tid] = sArr[idx];
    ee[tid] = eArr[idx];
}

// ---------------- NMS suppression bitmask ----------------
__global__ __launch_bounds__(256) void nms_mask_kernel(const float* __restrict__ ss, const float* __restrict__ ee,
                                                       unsigned long long* __restrict__ mask) {
    int g = blockIdx.x * 256 + threadIdx.x;
    int i = g >> 4, w = g & 15;
    float si = ss[i], ei = ee[i];
    unsigned long long bits = 0ull;
#pragma unroll 1
    for (int jj = 0; jj < 64; jj++) {
        int j = w * 64 + jj;
        if (j > i) {
            float sj = ss[j], ej = ee[j];
            float inter = fmaxf(0.f, fminf(ei, ej) - fmaxf(si, sj));
            float uni = (ej - sj) + (ei - si) - inter;
            float iou = inter / fmaxf(uni, 1e-8f);
            if (iou > 0.7f) bits |= (1ull << jj);
        }
    }
    mask[(size_t)i * 16 + w] = bits;
}

// ---------------- NMS scan (readlane scalar-pipe) + partition + gather ----------------
__device__ __forceinline__ unsigned long long readlane64(unsigned long long v, int i) {
    unsigned int lo = (unsigned int)__builtin_amdgcn_readlane((int)(unsigned int)(v & 0xFFFFFFFFull), i);
    unsigned int hi = (unsigned int)__builtin_amdgcn_readlane((int)(unsigned int)(v >> 32), i);
    return ((unsigned long long)hi << 32) | (unsigned long long)lo;
}

__global__ __launch_bounds__(64) void nms_select_kernel(const unsigned long long* __restrict__ mask,
                                                        const int* __restrict__ topI,
                                                        const float* __restrict__ ss, const float* __restrict__ ee,
                                                        const float* __restrict__ cls2, const float* __restrict__ off2,
                                                        int* __restrict__ stA, int* __restrict__ enA,
                                                        float* __restrict__ out) {
    int lane = threadIdx.x;
    unsigned long long keepW[16];
#pragma unroll 1
    for (int b = 0; b < 16; b++) {
        unsigned long long accv = 0ull;
#pragma unroll 1
        for (int a = 0; a < b; a++) {
            unsigned long long m = mask[(size_t)(a * 64 + lane) * 16 + b];
            unsigned long long kb = (keepW[a] >> lane) & 1ull;
            accv |= m & (0ull - kb);
        }
#pragma unroll
        for (int sft = 1; sft < 64; sft <<= 1) accv |= __shfl_xor(accv, sft);
        unsigned long long diag = mask[(size_t)(b * 64 + lane) * 16 + b];
        unsigned long long rem = accv;
#pragma unroll
        for (int i = 0; i < 64; i++) {
            unsigned long long di = readlane64(diag, i);
            if (!((rem >> i) & 1ull)) rem |= di;
        }
        keepW[b] = ~rem;
    }
    int total = 0;
    int prefix[16];
#pragma unroll
    for (int b = 0; b < 16; b++) { prefix[b] = total; total += __popcll(keepW[b]); }
#pragma unroll 1
    for (int b = 0; b < 16; b++) {
        int tid = b * 64 + lane;
        unsigned long long keep64 = keepW[b];
        unsigned long long below = (lane == 0) ? 0ull : (keep64 << (64 - lane));
        int keptBefore = prefix[b] + __popcll(below);
        int kp = (int)((keep64 >> lane) & 1ull);
        int pos = kp ? keptBefore : (total + tid - keptBefore);
        if (pos < 128) {
            int orig = topI[tid];
            float ps = ss[tid], pe = ee[tid];
            out[pos * 2 + 0] = cls2[orig * 2 + 0];
            out[pos * 2 + 1] = cls2[orig * 2 + 1];
            out[256 + pos * 2 + 0] = off2[orig * 2 + 0];
            out[256 + pos * 2 + 1] = off2[orig * 2 + 1];
            float bc = (ps + pe) * 0.5f, bh = (pe - ps) * 0.5f;
            int st = (int)fminf(fmaxf(floorf(bc - bh), 0.f), 767.f);
            int en = (int)fminf(fmaxf(ceilf(bc + bh), 0.f), 767.f);
            if (en < st) en = st;
            stA[pos] = st;
            enA[pos] = en;
        }
    }
}

// ---------------- ROI max pool -> 898-row hi/lo slab [row c+1][2048] ----------------
__global__ __launch_bounds__(256) void roi_slab_kernel(const float* __restrict__ f,
                                                       const int* __restrict__ stA, const int* __restrict__ enA,
                                                       unsigned short* __restrict__ Xs) {
    int col = blockIdx.x;  // 0..895
    int n = col / 7, b = col - n * 7;
    int st = stA[n], en = enA[n];
    int ln = en - st + 1;
    int bs = st + (b * ln) / 7;
    int be = st + ((b + 1) * ln + 6) / 7 - 1;
    unsigned short* Xh = Xs;
    unsigned short* Xl = Xs + (size_t)898 * 2048;
    int tid = threadIdx.x;
#pragma unroll 1
    for (int j = 0; j < 8; j++) {
        int ci = tid + 256 * j;
        const float* row = f + (size_t)ci * 768;
        float m = row[bs];
        for (int t = bs + 1; t <= be; t++) m = fmaxf(m, row[t]);
        unsigned short h = f2b(m);
        float lo = m - bf(h);
        size_t o = (size_t)(col + 1) * 2048 + ci;
        Xh[o] = h;
        Xl[o] = f2b(lo);
    }
}

__global__ __launch_bounds__(256) void zrow_wc2_kernel(unsigned short* __restrict__ Xs) {
    int i = blockIdx.x * 256 + threadIdx.x;
    if (i < 2048) {
        Xs[i] = 0;
        Xs[(size_t)897 * 2048 + i] = 0;
        Xs[(size_t)898 * 2048 + i] = 0;
        Xs[(size_t)898 * 2048 + (size_t)897 * 2048 + i] = 0;
    }
}

__global__ __launch_bounds__(256) void zseg_kernel(uint4* __restrict__ p, int n16) {
    int i = blockIdx.x * 256 + threadIdx.x;
    uint4 z = {0, 0, 0, 0};
    if (i < n16) p[i] = z;
}

extern "C" void kernel_launch(void* const* d_in, const int* in_sizes, int n_in,
                              void* d_out, int out_size, void* d_ws, size_t ws_size,
                              hipStream_t stream) {
    const float* IN[39];
    for (int i = 0; i < 39; i++) IN[i] = (const float*)d_in[i];
    const float* feature = IN[0];
    const float *b1f = IN[1], *b2f = IN[2], *b3 = IN[3], *b4 = IN[4], *b5 = IN[5], *b6 = IN[6];
    const float *bc1 = IN[7], *bc2 = IN[8], *boxb = IN[9], *boxw = IN[10];
    const float *clsb = IN[11], *clsw = IN[12];
    const float *fc1b = IN[13], *fc1w = IN[14], *fc2b = IN[15], *fc2w = IN[16];
    const float *fc3b = IN[17], *fc3w = IN[18];
    const float *sp1b = IN[19], *sp1w = IN[20], *sp2b = IN[21], *sp2w = IN[22];
    const float *sp3b = IN[23], *sp3w = IN[24], *sp4b = IN[25], *sp4w = IN[26];
    const float *spcb = IN[27], *spcw = IN[28], *spsb = IN[29], *spsw = IN[30];
    const float *w1f = IN[31], *w2f = IN[32], *w3w = IN[33], *w4w = IN[34];
    const float *w5w = IN[35], *w6w = IN[36], *wc1 = IN[37], *wc2 = IN[38];
    float* out = (float*)d_out;

    char* base = (char*)d_ws;
    float* G    = (float*)base;   // conv phase ≤25.2 MB; tower phase 14.68 MB
    float* part = (float*)base;   // fc1 partials + heads partials (phase-local)
    unsigned short* WrSmall = (unsigned short*)(base + 14680064);  // conv-phase small repacks (≤4.75 MB free)
    unsigned short* segSA = (unsigned short*)(base + 14680064);    // tower phase
    unsigned short* segSB = (unsigned short*)(base + 17055744);
    float* yA   = (float*)(base + 22020096);
    float* g1   = (float*)(base + 25690112);
    float* g2   = (float*)(base + 25952256);
    float* g3   = (float*)(base + 26083328);
    size_t off = 26148864;
    auto alloc = [&](size_t bytes) { void* p = base + off; off += (bytes + 63) & ~((size_t)63); return p; };
    unsigned short* Xt = (unsigned short*)alloc((size_t)898 * 2048 * 2 * 2);  // 7,356,416 B (898-slab fits!)
    float* fbuf = (float*)alloc((size_t)2048 * 768 * 4);
    unsigned short* WrWc2 = (unsigned short*)fbuf;                  // reused after roi_slab
    unsigned short* WrTower = (unsigned short*)Xt;                  // reused after wc2 conv
    float* hB   = (float*)alloc((size_t)512 * 768 * 4);
    float* clsS = (float*)alloc((size_t)20 * 768 * 4);
    float* segS = (float*)alloc((size_t)20 * 768 * 4);
    float* cls2 = (float*)alloc(7680 * 2 * 4);
    float* off2 = (float*)alloc(7680 * 2 * 4);
    float* scores = (float*)alloc(7680 * 4);
    float* sArr = (float*)alloc(7680 * 4);
    float* eArr = (float*)alloc(7680 * 4);
    float* ssS  = (float*)alloc(1024 * 4);
    float* eeS  = (float*)alloc(1024 * 4);
    unsigned long long* runs = (unsigned long long*)alloc((size_t)8192 * 8);
    unsigned long long* mask = (unsigned long long*)alloc((size_t)16384 * 8);
    int* topI = (int*)alloc(1024 * 4);
    int* stA = (int*)alloc(128 * 4);
    int* enA = (int*)alloc(128 * 4);

    // big-conv repack buffer (50.33 MB) — only if workspace allows
    size_t bigWrBytes = (size_t)2048 * 3 * 2 * 2048 * 2;
    unsigned short* WrBig = (unsigned short*)alloc(bigWrBytes);
    bool useBigWr = (off <= ws_size);

    dim3 blk(256);
    dim3 blk512(512);

    // ---- conv1: feature -> slab; W repack (if room) -> conv -> slab ----
    zeroXt_kernel<<<16, blk, 0, stream>>>(Xt, 2048);
    decomp_kernel<<<dim3(24, 64), blk, 0, stream>>>(feature, Xt, 2048);
    if (useBigWr) {
        repackW_kernel<<<49152, blk, 0, stream>>>(w1f, WrBig, 2048, 2048, 3);
        convmmW_kernel<3, 0><<<dim3(32, 6, 4), blk512, 0, stream>>>(WrBig, Xt, G, 2048, 2048, 4, 768, 770 * 2048);
    } else {
        convmm_kernel<<<dim3(32, 6, 4), blk512, 0, stream>>>(w1f, Xt, G, 2048, 2048, 4, 768, 770 * 2048);
    }
    finsum_x_kernel<<<dim3(32, 12), blk, 0, stream>>>(G, b1f, Xt, 2048, 4);
    // ---- conv2 ----
    if (useBigWr) {
        repackW_kernel<<<49152, blk, 0, stream>>>(w2f, WrBig, 2048, 2048, 3);
        convmmW_kernel<3, 0><<<dim3(32, 6, 4), blk512, 0, stream>>>(WrBig, Xt, G, 2048, 2048, 4, 768, 770 * 2048);
    } else {
        convmm_kernel<<<dim3(32, 6, 4), blk512, 0, stream>>>(w2f, Xt, G, 2048, 2048, 4, 768, 770 * 2048);
    }
    finsum_xf_kernel<<<dim3(32, 12), blk, 0, stream>>>(G, b2f, Xt, fbuf, 2048, 4);

    // ---- wc1 via repacked MFMA (TAPS=1 on conv2 slab) -> 512-slab ----
    repackW_kernel<<<4096, blk, 0, stream>>>(wc1, WrSmall, 512, 2048, 1);
    convmmW_kernel<1, 0><<<dim3(8, 6, 8), blk512, 0, stream>>>(WrSmall, Xt, G, 512, 2048, 8, 768, 770 * 2048);
    zeroXt_kernel<<<4, blk, 0, stream>>>(Xt, 512);
    finsum_x_kernel<<<dim3(8, 12), blk, 0, stream>>>(G, bc1, Xt, 512, 8);

    // ---- sp1..sp4 via repacked MFMA ----
    repackW_kernel<<<3072, blk, 0, stream>>>(sp1w, WrSmall, 512, 512, 3);
    convmmW_kernel<3, 0><<<dim3(8, 6, 8), blk512, 0, stream>>>(WrSmall, Xt, G, 512, 512, 8, 768, 770 * 512);
    finsum_x_kernel<<<dim3(8, 12), blk, 0, stream>>>(G, sp1b, Xt, 512, 8);
    repackW_kernel<<<3072, blk, 0, stream>>>(sp2w, WrSmall, 512, 512, 3);
    convmmW_kernel<3, 0><<<dim3(8, 6, 8), blk512, 0, stream>>>(WrSmall, Xt, G, 512, 512, 8, 768, 770 * 512);
    finsum_x_kernel<<<dim3(8, 12), blk, 0, stream>>>(G, sp2b, Xt, 512, 8);
    repackW_kernel<<<3072, blk, 0, stream>>>(sp3w, WrSmall, 512, 512, 3);
    convmmW_kernel<3, 0><<<dim3(8, 6, 8), blk512, 0, stream>>>(WrSmall, Xt, G, 512, 512, 8, 768, 770 * 512);
    finsum_x_kernel<<<dim3(8, 12), blk, 0, stream>>>(G, sp3b, Xt, 512, 8);
    repackW_kernel<<<3072, blk, 0, stream>>>(sp4w, WrSmall, 512, 512, 3);
    convmmW_kernel<3, 0><<<dim3(8, 6, 8), blk512, 0, stream>>>(WrSmall, Xt, G, 512, 512, 8, 768, 770 * 512);
    finsum_f_kernel<<<1536, blk, 0, stream>>>(G, sp4b, hB, 512, 8, 768, 1);  // relu

    // ---- heads (split-K S=8; partials in dead G region) ----
    gemm_kernel<0, 0><<<dim3(1, 12, 8), blk, 0, stream>>>(spcw, hB, spcb, part, 20, 512, 768, 768, 8, 0);
    finalize_kernel<<<60, blk, 0, stream>>>(part, clsS, spcb, 20, 20, 768, 8, 0);
    gemm_kernel<0, 0><<<dim3(1, 12, 8), blk, 0, stream>>>(spsw, hB, spsb, part, 20, 512, 768, 768, 8, 0);
    finalize_kernel<<<60, blk, 0, stream>>>(part, segS, spsb, 20, 20, 768, 8, 0);

    // ---- proposal decode / top-k / NMS ----
    proposal_kernel<<<30, blk, 0, stream>>>(clsS, segS, cls2, off2, scores, sArr, eArr);
    sortA_kernel<<<8, 1024, 0, stream>>>(scores, runs);
    sortB_kernel<<<1, 1024, 0, stream>>>(runs, sArr, eArr, topI, ssS, eeS);
    nms_mask_kernel<<<64, blk, 0, stream>>>(ssS, eeS, mask);
    nms_select_kernel<<<1, 64, 0, stream>>>(mask, topI, ssS, eeS, cls2, off2, stA, enA, out);

    // ---- ROI pool -> wc2 slab (Xt, now correctly 898-row sized) ----
    zrow_wc2_kernel<<<8, blk, 0, stream>>>(Xt);
    roi_slab_kernel<<<896, blk, 0, stream>>>(fbuf, stA, enA, Xt);
    zseg_kernel<<<1160, blk, 0, stream>>>((uint4*)segSA, 296960);

    // ---- classifier tower via repacked MFMA ----
    repackW_kernel<<<4096, blk, 0, stream>>>(wc2, WrWc2, 512, 2048, 1);  // fbuf dead after roi
    convmmW_kernel<1, 0><<<dim3(8, 7, 8), blk512, 0, stream>>>(WrWc2, Xt, G, 512, 2048, 8, 896, 898 * 2048);
    finsum_seg_kernel<<<dim3(8, 14), blk, 0, stream>>>(G, bc2, segSA, 8, 0);
    repackW_kernel<<<3072, blk, 0, stream>>>(w3w, WrTower, 512, 512, 3);  // Xt dead after wc2 conv
    convmmW_kernel<3, 1><<<dim3(8, 7, 8), blk512, 0, stream>>>(WrTower, segSA, G, 512, 512, 8, 896, 1160 * 512);
    finsum_seg_kernel<<<dim3(8, 14), blk, 0, stream>>>(G, b3, segSB, 8, 0);
    repackW_kernel<<<3072, blk, 0, stream>>>(w4w, WrTower, 512, 512, 3);
    convmmW_kernel<3, 1><<<dim3(8, 7, 8), blk512, 0, stream>>>(WrTower, segSB, G, 512, 512, 8, 896, 1160 * 512);
    finsum_seg_kernel<<<dim3(8, 14), blk, 0, stream>>>(G, b4, segSA, 8, 1);  // relu
    repackW_kernel<<<3072, blk, 0, stream>>>(w5w, WrTower, 512, 512, 3);
    convmmW_kernel<3, 1><<<dim3(8, 7, 8), blk512, 0, stream>>>(WrTower, segSA, G, 512, 512, 8, 896, 1160 * 512);
    finsum_seg_kernel<<<dim3(8, 14), blk, 0, stream>>>(G, b5, segSB, 8, 0);
    repackW_kernel<<<3072, blk, 0, stream>>>(w6w, WrTower, 512, 512, 3);
    convmmW_kernel<3, 1><<<dim3(8, 7, 8), blk512, 0, stream>>>(WrTower, segSB, G, 512, 512, 8, 896, 1160 * 512);
    finsum_f_kernel<<<1792, blk, 0, stream>>>(G, b6, yA, 512, 8, 896, 1);  // relu -> fp32 [512][896]

    // ---- fc1 (relu), fc2, fc3, output heads (fp32) ----
    gemm_kernel<1, 0><<<dim3(8, 2, 28), blk, 0, stream>>>(fc1w, yA, fc1b, part, 512, 3584, 128, 128, 28, 0);
    finalize_kernel<<<256, blk, 0, stream>>>(part, g1, fc1b, 512, 512, 128, 28, 1);

    gemm_kernel<0, 0><<<dim3(4, 2, 4), blk, 0, stream>>>(fc2w, g1, fc2b, part, 256, 512, 128, 128, 4, 0);
    finalize_kernel<<<128, blk, 0, stream>>>(part, g2, fc2b, 256, 256, 128, 4, 0);
    gemm_kernel<0, 0><<<dim3(2, 2, 2), blk, 0, stream>>>(fc3w, g2, fc3b, part, 128, 256, 128, 128, 2, 0);
    finalize_kernel<<<64, blk, 0, stream>>>(part, g3, fc3b, 128, 128, 128, 2, 0);

    gemm_kernel<0, 1><<<dim3(1, 2, 1), blk, 0, stream>>>(clsw, g3, clsb, out, 21, 128, 128, 128, 1, 0);
    gemm_kernel<0, 2><<<dim3(1, 2, 1), blk, 0, stream>>>(boxw, g3, boxb, out, 40, 128, 128, 128, 1, 0);
}

// Round 10
// 1121.900 us; speedup vs baseline: 1.1951x; 1.1951x over previous
//
#include <hip/hip_runtime.h>

typedef __attribute__((ext_vector_type(8))) short short8;
typedef __attribute__((ext_vector_type(4))) float float4v;

__device__ __forceinline__ float bf(unsigned short u) {
    return __uint_as_float(((unsigned int)u) << 16);
}
__device__ __forceinline__ unsigned short f2b(float f) {
    unsigned int u = __float_as_uint(f);
    unsigned int r = (u + 0x7FFFu + ((u >> 16) & 1u)) >> 16;
    return (unsigned short)r;
}

__constant__ float c_anchors[10] = {2.f,4.f,5.f,6.f,8.f,9.f,10.f,12.f,14.f,16.f};

// ============ W repack: fp32 [CO][CI][TAPS] -> bf16 hi/lo Wr[((co*TAPS+t)*2+p)*CI+ci] ============
__global__ __launch_bounds__(256) void repackW_kernel(const float* __restrict__ W,
                                                      unsigned short* __restrict__ Wr,
                                                      int CO, int CI, int TAPS) {
    int i = blockIdx.x * 256 + threadIdx.x;
    int n = CO * CI * TAPS;
    if (i >= n) return;
    int cit = CI * TAPS;
    int co = i / cit;
    int rem = i - co * cit;
    int ci = rem / TAPS;
    int t = rem - ci * TAPS;
    float v = W[i];
    unsigned short h = f2b(v);
    unsigned short l = f2b(v - bf(h));
    size_t o = ((size_t)(co * TAPS + t) * 2) * CI + ci;
    Wr[o] = h;
    Wr[o + CI] = l;
}

// ============ Xt helpers: transposed bf16 hi/lo slab, planes h/l ============
__global__ __launch_bounds__(256) void zeroXt_kernel(unsigned short* __restrict__ Xt, int CI) {
    int i = blockIdx.x * 256 + threadIdx.x;
    if (i < 2 * CI) {
        int row = (i >= CI) ? 769 : 0;
        int co = (i >= CI) ? (i - CI) : i;
        Xt[(size_t)row * CI + co] = 0;
        Xt[(size_t)770 * CI + (size_t)row * CI + co] = 0;
    }
}

// src fp32 [CI][768] -> Xt rows 1..768 (row l+1 = X[:,l]), hi/lo planes
__global__ __launch_bounds__(256) void decomp_kernel(const float* __restrict__ src,
                                                     unsigned short* __restrict__ Xt, int CI) {
    __shared__ float T[32][33];
    int l0 = blockIdx.x * 32, ci0 = blockIdx.y * 32;
    int tid = threadIdx.x;
#pragma unroll
    for (int i = 0; i < 4; i++) {
        int slot = tid + 256 * i;
        int r = slot >> 5, c = slot & 31;
        T[r][c] = src[(size_t)(ci0 + r) * 768 + l0 + c];
    }
    __syncthreads();
    unsigned short* Xh = Xt;
    unsigned short* Xl = Xt + (size_t)770 * CI;
#pragma unroll
    for (int i = 0; i < 4; i++) {
        int slot = tid + 256 * i;
        int li = slot >> 5, cc = slot & 31;
        float v = T[cc][li];
        unsigned short h = f2b(v);
        float lo = v - bf(h);
        size_t o = (size_t)(l0 + li + 1) * CI + ci0 + cc;
        Xh[o] = h;
        Xl[o] = f2b(lo);
    }
}

// ============ repacked-W MFMA conv-as-GEMM: A staged via LDS with vector copies ============
// SEGM=0: slab row of col c = c+1; SEGM=1: row = (c/7)*9 + c%7 + 1
template <int TAPS, int SEGM>
__global__ __launch_bounds__(512, 6) void convmmW_kernel(const unsigned short* __restrict__ Wr,
                                                         const unsigned short* __restrict__ Xt,
                                                         float* __restrict__ G,
                                                         int CO, int CI, int S, int NCOL, int planeElems) {
    constexpr int RS = TAPS * 32 + 8;
    constexpr int BROWS = SEGM ? 168 : 130;
    constexpr int ASLOTS = 64 * TAPS * 8;  // short8 slots per K-iter (1536 or 512)
    __shared__ unsigned short At[2][64 * RS];
    __shared__ unsigned short Bt[2][BROWS * 40];
    int tid = threadIdx.x;
    int lane = tid & 63, wid = tid >> 6;
    int q = lane >> 4, ln = lane & 15;
    int co0 = blockIdx.x * 64;
    int c0 = blockIdx.y * 128;
    int s = blockIdx.z;
    int kPer = CI / S, cis = s * kPer;
    const unsigned short* Xh = Xt;
    const unsigned short* Xl = Xt + planeElems;
    int row0 = SEGM ? ((c0 / 7) * 9 + c0 % 7) : c0;

    float4v zero4 = {0.f, 0.f, 0.f, 0.f};
    float4v acc[2][2];
    acc[0][0] = zero4; acc[0][1] = zero4; acc[1][0] = zero4; acc[1][1] = zero4;

    int wave_m = (wid >> 2) * 32;
    int wave_n = (wid & 3) * 32;

    int rowb[2];
#pragma unroll
    for (int nf = 0; nf < 2; nf++) {
        int col = c0 + wave_n + nf * 16 + ln;
        rowb[nf] = SEGM ? ((col / 7) * 9 + col % 7 - row0) : (wave_n + nf * 16 + ln);
    }

    for (int kb = 0; kb < kPer; kb += 32) {
        int cib = cis + kb;
        // stage A: pure 16B copies from repacked W (no decompose VALU)
#pragma unroll
        for (int i = 0; i < ASLOTS / 512; i++) {
            int slot = tid + 512 * i;
            int row = slot / (TAPS * 8);
            int rem = slot - row * (TAPS * 8);
            int t = rem >> 3;
            int p = (rem >> 2) & 1;
            int qq = rem & 3;
            const unsigned short* src = Wr + ((size_t)((co0 + row) * TAPS + t) * 2 + p) * CI + cib + qq * 8;
            *(short8*)&At[p][row * RS + t * 32 + qq * 8] = *(const short8*)src;
        }
        // stage B slab: BROWS rows, 32 ci, both planes, 16B chunks
#pragma unroll
        for (int i = 0; i < 3; i++) {
            int slot = tid + 512 * i;
            if (slot < BROWS * 8) {
                int p = slot >= BROWS * 4 ? 1 : 0;
                int rem = slot - p * BROWS * 4;
                int r = rem >> 2, qq = rem & 3;
                const unsigned short* src = (p ? Xl : Xh) + (size_t)(row0 + r) * CI + cib + qq * 8;
                short8 v = *(const short8*)src;
                *(short8*)&Bt[p][r * 40 + qq * 8] = v;
            }
        }
        __syncthreads();
#pragma unroll
        for (int t = 0; t < TAPS; t++) {
            int shift = (TAPS == 1) ? 1 : t;
            short8 bh[2], bl[2];
#pragma unroll
            for (int nf = 0; nf < 2; nf++) {
                int rrow = rowb[nf] + shift;
                bh[nf] = *(const short8*)&Bt[0][rrow * 40 + q * 8];
                bl[nf] = *(const short8*)&Bt[1][rrow * 40 + q * 8];
            }
#pragma unroll
            for (int mf = 0; mf < 2; mf++) {
                int mrow = wave_m + mf * 16 + ln;
                short8 ah = *(const short8*)&At[0][mrow * RS + t * 32 + q * 8];
                short8 al = *(const short8*)&At[1][mrow * RS + t * 32 + q * 8];
#pragma unroll
                for (int nf = 0; nf < 2; nf++) {
                    acc[mf][nf] = __builtin_amdgcn_mfma_f32_16x16x32_bf16(ah, bh[nf], acc[mf][nf], 0, 0, 0);
                    acc[mf][nf] = __builtin_amdgcn_mfma_f32_16x16x32_bf16(ah, bl[nf], acc[mf][nf], 0, 0, 0);
                    acc[mf][nf] = __builtin_amdgcn_mfma_f32_16x16x32_bf16(al, bh[nf], acc[mf][nf], 0, 0, 0);
                }
            }
        }
        __syncthreads();
    }
    float* Gz = G + (size_t)s * CO * NCOL;
#pragma unroll
    for (int mf = 0; mf < 2; mf++)
#pragma unroll
        for (int nf = 0; nf < 2; nf++) {
            int col = c0 + wave_n + nf * 16 + ln;
            int rowb2 = co0 + wave_m + mf * 16 + q * 4;
#pragma unroll
            for (int r = 0; r < 4; r++)
                Gz[(size_t)(rowb2 + r) * NCOL + col] = acc[mf][nf][r];
        }
}

// ============ legacy in-kernel-decompose conv (fallback for big convs if ws too small) ============
__global__ __launch_bounds__(512, 6) void convmm_kernel(const float* __restrict__ W,
                                                        const unsigned short* __restrict__ Xt,
                                                        float* __restrict__ G,
                                                        int CO, int CI, int S, int NCOL, int planeElems) {
    constexpr int RS = 3 * 32 + 8;
    __shared__ unsigned short At[2][64 * RS];
    __shared__ unsigned short Bt[2][130 * 40];
    int tid = threadIdx.x;
    int lane = tid & 63, wid = tid >> 6;
    int q = lane >> 4, ln = lane & 15;
    int co0 = blockIdx.x * 64;
    int c0 = blockIdx.y * 128;
    int s = blockIdx.z;
    int kPer = CI / S, cis = s * kPer;
    const unsigned short* Xh = Xt;
    const unsigned short* Xl = Xt + planeElems;

    float4v zero4 = {0.f, 0.f, 0.f, 0.f};
    float4v acc[2][2];
    acc[0][0] = zero4; acc[0][1] = zero4; acc[1][0] = zero4; acc[1][1] = zero4;

    int wave_m = (wid >> 2) * 32;
    int wave_n = (wid & 3) * 32;

    for (int kb = 0; kb < kPer; kb += 32) {
        int cib = cis + kb;
#pragma unroll
        for (int i = 0; i < 2; i++) {
            int slot = tid + 512 * i;
            int row = slot >> 4, cc0 = (slot & 15) * 2;
            const float* wp = W + ((size_t)(co0 + row) * CI + cib + cc0) * 3;
            float fa[6];
#pragma unroll
            for (int j = 0; j < 6; j++) fa[j] = wp[j];
#pragma unroll
            for (int t = 0; t < 3; t++) {
                unsigned short h0 = f2b(fa[t]);
                unsigned short h1 = f2b(fa[t + 3]);
                unsigned short e0 = f2b(fa[t] - bf(h0));
                unsigned short e1 = f2b(fa[t + 3] - bf(h1));
                *(unsigned int*)&At[0][row * RS + t * 32 + cc0] =
                    (unsigned int)h0 | ((unsigned int)h1 << 16);
                *(unsigned int*)&At[1][row * RS + t * 32 + cc0] =
                    (unsigned int)e0 | ((unsigned int)e1 << 16);
            }
        }
#pragma unroll
        for (int i = 0; i < 3; i++) {
            int slot = tid + 512 * i;
            if (slot < 1040) {
                int p = slot >= 520 ? 1 : 0;
                int rem = slot - p * 520;
                int r = rem >> 2, qq = rem & 3;
                const unsigned short* src = (p ? Xl : Xh) + (size_t)(c0 + r) * CI + cib + qq * 8;
                short8 v = *(const short8*)src;
                *(short8*)&Bt[p][r * 40 + qq * 8] = v;
            }
        }
        __syncthreads();
#pragma unroll
        for (int t = 0; t < 3; t++) {
            short8 bh[2], bl[2];
#pragma unroll
            for (int nf = 0; nf < 2; nf++) {
                int rrow = wave_n + nf * 16 + ln + t;
                bh[nf] = *(const short8*)&Bt[0][rrow * 40 + q * 8];
                bl[nf] = *(const short8*)&Bt[1][rrow * 40 + q * 8];
            }
#pragma unroll
            for (int mf = 0; mf < 2; mf++) {
                int mrow = wave_m + mf * 16 + ln;
                short8 ah = *(const short8*)&At[0][mrow * RS + t * 32 + q * 8];
                short8 al = *(const short8*)&At[1][mrow * RS + t * 32 + q * 8];
#pragma unroll
                for (int nf = 0; nf < 2; nf++) {
                    acc[mf][nf] = __builtin_amdgcn_mfma_f32_16x16x32_bf16(ah, bh[nf], acc[mf][nf], 0, 0, 0);
                    acc[mf][nf] = __builtin_amdgcn_mfma_f32_16x16x32_bf16(ah, bl[nf], acc[mf][nf], 0, 0, 0);
                    acc[mf][nf] = __builtin_amdgcn_mfma_f32_16x16x32_bf16(al, bh[nf], acc[mf][nf], 0, 0, 0);
                }
            }
        }
        __syncthreads();
    }
    float* Gz = G + (size_t)s * CO * NCOL;
#pragma unroll
    for (int mf = 0; mf < 2; mf++)
#pragma unroll
        for (int nf = 0; nf < 2; nf++) {
            int col = c0 + wave_n + nf * 16 + ln;
            int rowb2 = co0 + wave_m + mf * 16 + q * 4;
#pragma unroll
            for (int r = 0; r < 4; r++)
                Gz[(size_t)(rowb2 + r) * NCOL + col] = acc[mf][nf][r];
        }
}

// finalize: sum P planes + bias -> transposed bf16 hi/lo Xt (770-row slab)
__global__ __launch_bounds__(256) void finsum_x_kernel(const float* __restrict__ G,
                                                       const float* __restrict__ bias,
                                                       unsigned short* __restrict__ Xt,
                                                       int CO, int P) {
    __shared__ float T[64][65];
    int co0 = blockIdx.x * 64, l0 = blockIdx.y * 64;
    int tid = threadIdx.x;
#pragma unroll 1
    for (int i = 0; i < 16; i++) {
        int slot = tid + 256 * i;
        int r = slot >> 6, c = slot & 63;
        float v = bias[co0 + r];
        for (int p = 0; p < P; p++) v += G[((size_t)p * CO + co0 + r) * 768 + l0 + c];
        T[r][c] = v;
    }
    __syncthreads();
    unsigned short* Xh = Xt;
    unsigned short* Xl = Xt + (size_t)770 * CO;
#pragma unroll 1
    for (int i = 0; i < 16; i++) {
        int slot = tid + 256 * i;
        int li = slot >> 6, ci = slot & 63;
        float v = T[ci][li];
        unsigned short h = f2b(v);
        float lo = v - bf(h);
        size_t o = (size_t)(l0 + li + 1) * CO + co0 + ci;
        Xh[o] = h;
        Xl[o] = f2b(lo);
    }
}

// finalize: sum P planes + bias -> 770-slab AND fp32 [CO][768]
__global__ __launch_bounds__(256) void finsum_xf_kernel(const float* __restrict__ G,
                                                        const float* __restrict__ bias,
                                                        unsigned short* __restrict__ Xt,
                                                        float* __restrict__ outF,
                                                        int CO, int P) {
    __shared__ float T[64][65];
    int co0 = blockIdx.x * 64, l0 = blockIdx.y * 64;
    int tid = threadIdx.x;
#pragma unroll 1
    for (int i = 0; i < 16; i++) {
        int slot = tid + 256 * i;
        int r = slot >> 6, c = slot & 63;
        float v = bias[co0 + r];
        for (int p = 0; p < P; p++) v += G[((size_t)p * CO + co0 + r) * 768 + l0 + c];
        T[r][c] = v;
        outF[(size_t)(co0 + r) * 768 + l0 + c] = v;
    }
    __syncthreads();
    unsigned short* Xh = Xt;
    unsigned short* Xl = Xt + (size_t)770 * CO;
#pragma unroll 1
    for (int i = 0; i < 16; i++) {
        int slot = tid + 256 * i;
        int li = slot >> 6, ci = slot & 63;
        float v = T[ci][li];
        unsigned short h = f2b(v);
        float lo = v - bf(h);
        size_t o = (size_t)(l0 + li + 1) * CO + co0 + ci;
        Xh[o] = h;
        Xl[o] = f2b(lo);
    }
}

// finalize: sum P planes + bias -> segmented slab [1160][512] hi/lo (+relu)
__global__ __launch_bounds__(256) void finsum_seg_kernel(const float* __restrict__ G,
                                                         const float* __restrict__ bias,
                                                         unsigned short* __restrict__ Xs,
                                                         int P, int relu) {
    __shared__ float T[64][65];
    int co0 = blockIdx.x * 64, c0 = blockIdx.y * 64;
    int tid = threadIdx.x;
#pragma unroll 1
    for (int i = 0; i < 16; i++) {
        int slot = tid + 256 * i;
        int r = slot >> 6, c = slot & 63;
        float v = bias[co0 + r];
        for (int p = 0; p < P; p++) v += G[((size_t)p * 512 + co0 + r) * 896 + c0 + c];
        if (relu) v = fmaxf(v, 0.f);
        T[r][c] = v;
    }
    __syncthreads();
    unsigned short* Xh = Xs;
    unsigned short* Xl = Xs + (size_t)1160 * 512;
#pragma unroll 1
    for (int i = 0; i < 16; i++) {
        int slot = tid + 256 * i;
        int li = slot >> 6, ci = slot & 63;
        float v = T[ci][li];
        int c = c0 + li;
        int row = (c / 7) * 9 + c % 7 + 1;
        unsigned short h = f2b(v);
        float lo = v - bf(h);
        size_t o = (size_t)row * 512 + co0 + ci;
        Xh[o] = h;
        Xl[o] = f2b(lo);
    }
}

// finalize: sum P planes + bias (+relu) -> fp32 [CO][ncol]
__global__ __launch_bounds__(256) void finsum_f_kernel(const float* __restrict__ G,
                                                       const float* __restrict__ bias,
                                                       float* __restrict__ out,
                                                       int CO, int P, int ncol, int relu) {
    int i = blockIdx.x * 256 + threadIdx.x;
    if (i >= CO * ncol) return;
    int r = i / ncol, c = i - r * ncol;
    float v = bias[r];
    for (int p = 0; p < P; p++) v += G[((size_t)p * CO + r) * ncol + c];
    if (relu) v = fmaxf(v, 0.f);
    out[i] = v;
}

// ---------------- finalize for fp32 split-K gemm path ----------------
__global__ __launch_bounds__(256) void finalize_kernel(const float* __restrict__ part,
                                                       float* __restrict__ out,
                                                       const float* __restrict__ bias,
                                                       int RPAD, int R, int NCOLS, int S, int relu) {
    int i = blockIdx.x * 256 + threadIdx.x;
    int total = R * NCOLS;
    if (i >= total) return;
    int r = i / NCOLS;
    int c = i - r * NCOLS;
    float v = 0.f;
    for (int s = 0; s < S; s++) v += part[((size_t)s * RPAD + r) * NCOLS + c];
    v += bias[r];
    if (relu) v = fmaxf(v, 0.f);
    out[i] = v;
}

// ---------------- fp32 gather-GEMM (heads, fc1-3, output heads) ----------------
template <int MODE, int EPI>
__global__ __launch_bounds__(256) void gemm_kernel(const float* __restrict__ W,
                                                   const float* __restrict__ B,
                                                   const float* __restrict__ bias,
                                                   float* __restrict__ outF,
                                                   int R, int K, int NCOLS, int LDB, int S, int relu) {
    __shared__ __align__(16) float Bt[16][68];
    __shared__ __align__(16) float Wt[16][68];
    int tid = threadIdx.x;
    int tx = tid & 15, ty = tid >> 4;
    int r0 = blockIdx.x * 64, c0 = blockIdx.y * 64, s = blockIdx.z;
    int kPer = K / S;
    int k0s = s * kPer;
    float acc[4][4] = {};
    for (int kb = 0; kb < kPer; kb += 16) {
        int k0 = k0s + kb;
        {
            int rr = r0 + (tid >> 2);
            int q = tid & 3;
            float4 wv4 = {0.f, 0.f, 0.f, 0.f};
            if (rr < R) wv4 = *(const float4*)(W + (size_t)rr * K + k0 + q * 4);
            Wt[q * 4 + 0][tid >> 2] = wv4.x;
            Wt[q * 4 + 1][tid >> 2] = wv4.y;
            Wt[q * 4 + 2][tid >> 2] = wv4.z;
            Wt[q * 4 + 3][tid >> 2] = wv4.w;
        }
#pragma unroll
        for (int p = 0; p < 4; p++) {
            int kk = p * 4 + (tid >> 6);
            int c = tid & 63;
            int k = k0 + kk;
            int col = c0 + c;
            float v;
            if (MODE == 0) {
                v = B[(size_t)k * LDB + col];
            } else {
                int co = k / 7;
                int b7 = k - co * 7;
                v = B[(size_t)co * 896 + col * 7 + b7];
            }
            Bt[kk][c] = v;
        }
        __syncthreads();
#pragma unroll
        for (int kk = 0; kk < 16; kk++) {
            float4 bv = *(const float4*)&Bt[kk][tx * 4];
            float4 wv = *(const float4*)&Wt[kk][ty * 4];
            float bb[4] = {bv.x, bv.y, bv.z, bv.w};
            float ww[4] = {wv.x, wv.y, wv.z, wv.w};
#pragma unroll
            for (int i = 0; i < 4; i++)
#pragma unroll
                for (int j = 0; j < 4; j++)
                    acc[i][j] = fmaf(ww[i], bb[j], acc[i][j]);
        }
        __syncthreads();
    }
    if (EPI == 0) {
        if (S > 1) {
#pragma unroll
            for (int i = 0; i < 4; i++) {
                int r = r0 + ty * 4 + i;
                if (r < R) {
                    float4 o = {acc[i][0], acc[i][1], acc[i][2], acc[i][3]};
                    *(float4*)&outF[((size_t)s * R + r) * NCOLS + c0 + tx * 4] = o;
                }
            }
        } else {
#pragma unroll
            for (int i = 0; i < 4; i++) {
                int r = r0 + ty * 4 + i;
                if (r < R) {
                    float bv = bias[r];
#pragma unroll
                    for (int j = 0; j < 4; j++) {
                        float v = acc[i][j] + bv;
                        if (relu) v = fmaxf(v, 0.f);
                        outF[(size_t)r * NCOLS + c0 + tx * 4 + j] = v;
                    }
                }
            }
        }
    } else {
#pragma unroll
        for (int i = 0; i < 4; i++) {
            int r = r0 + ty * 4 + i;
            if (r < R) {
                float bv = bias[r];
#pragma unroll
                for (int j = 0; j < 4; j++) {
                    int col = c0 + tx * 4 + j;
                    float v = acc[i][j] + bv;
                    if (EPI == 1) outF[512 + col * 21 + r] = v;
                    else outF[3200 + col * 40 + r] = v;
                }
            }
        }
    }
}

// ---------------- proposals: softmax, anchor decode ----------------
__global__ __launch_bounds__(256) void proposal_kernel(const float* __restrict__ clsS,
                                                       const float* __restrict__ segS,
                                                       float* __restrict__ cls2, float* __restrict__ off2,
                                                       float* __restrict__ scores,
                                                       float* __restrict__ sArr, float* __restrict__ eArr) {
    int i = blockIdx.x * 256 + threadIdx.x;
    if (i >= 7680) return;
    int l = i / 10;
    int a = i - l * 10;
    float c0 = clsS[(a * 2 + 0) * 768 + l];
    float c1 = clsS[(a * 2 + 1) * 768 + l];
    cls2[i * 2] = c0;
    cls2[i * 2 + 1] = c1;
    float m = fmaxf(c0, c1);
    float e0 = expf(c0 - m), e1 = expf(c1 - m);
    scores[i] = e1 / (e0 + e1);
    float o0 = segS[(a * 2 + 0) * 768 + l];
    float o1 = segS[(a * 2 + 1) * 768 + l];
    off2[i * 2] = o0;
    off2[i * 2 + 1] = o1;
    float ah = c_anchors[a] * 0.5f;
    float ac = (float)l + 0.5f;
    float c = ac + o0 * (2.f * ah);
    float hl = ah * expf(o1);
    sArr[i] = fminf(fmaxf(c - hl, 0.f), 768.f);
    eArr[i] = fminf(fmaxf(c + hl, 0.f), 768.f);
}

// ---------------- bitonic top-k phase A ----------------
__global__ __launch_bounds__(1024) void sortA_kernel(const float* __restrict__ scores,
                                                     unsigned long long* __restrict__ runs) {
    __shared__ unsigned long long kk[1024];
    int tid = threadIdx.x;
    int gbase = blockIdx.x * 1024;
    int gi = gbase + tid;
    unsigned long long key = 0ull;
    if (gi < 7680) {
        unsigned int sb = __float_as_uint(scores[gi]);
        key = ((unsigned long long)sb << 32) | (unsigned long long)(0xFFFFFFFFu - (unsigned)gi);
    }
    kk[tid] = key;
    __syncthreads();
    for (int k = 2; k <= 1024; k <<= 1) {
        for (int j = k >> 1; j > 0; j >>= 1) {
            int ixj = tid ^ j;
            if (ixj > tid) {
                unsigned long long a = kk[tid], b = kk[ixj];
                bool descend = ((tid & k) == 0);
                if (descend ? (a < b) : (a > b)) { kk[tid] = b; kk[ixj] = a; }
            }
            __syncthreads();
        }
    }
    runs[gbase + tid] = kk[tid];
}

// ---------------- phase B: tree-merge, exact top-1024 desc ----------------
__global__ __launch_bounds__(1024) void sortB_kernel(const unsigned long long* __restrict__ runs,
                                                     const float* __restrict__ sArr, const float* __restrict__ eArr,
                                                     int* __restrict__ topI,
                                                     float* __restrict__ ss, float* __restrict__ ee) {
    __shared__ unsigned long long S[8192];
    int tid = threadIdx.x;
#pragma unroll
    for (int m = 0; m < 8; m++) S[m * 1024 + tid] = runs[m * 1024 + tid];
    __syncthreads();
#pragma unroll 1
    for (int level = 0; level < 3; level++) {
        int span = 1024 << level;
        int nm = 4 >> level;
        for (int m = 0; m < nm; m++) {
            int baseA = m * (span * 2);
            int baseB = baseA + span;
            unsigned long long a = S[baseA + tid], b = S[baseB + 1023 - tid];
            S[baseA + tid] = (a > b) ? a : b;
        }
        __syncthreads();
        for (int j = 512; j > 0; j >>= 1) {
            for (int m = 0; m < nm; m++) {
                int baseA = m * (span * 2);
                int ixj = tid ^ j;
                if (ixj > tid) {
                    unsigned long long a = S[baseA + tid], b = S[baseA + ixj];
                    if (a < b) { S[baseA + tid] = b; S[baseA + ixj] = a; }
                }
            }
            __syncthreads();
        }
    }
    int idx = (int)(0xFFFFFFFFu - (unsigned int)(S[tid] & 0xFFFFFFFFull));
    topI[tid] = idx;
    ss[tid] = sArr[idx];
    ee[tid] = eArr[idx];
}

// ---------------- NMS suppression bitmask ----------------
__global__ __launch_bounds__(256) void nms_mask_kernel(const float* __restrict__ ss, const float* __restrict__ ee,
                                                       unsigned long long* __restrict__ mask) {
    int g = blockIdx.x * 256 + threadIdx.x;
    int i = g >> 4, w = g & 15;
    float si = ss[i], ei = ee[i];
    unsigned long long bits = 0ull;
#pragma unroll 1
    for (int jj = 0; jj < 64; jj++) {
        int j = w * 64 + jj;
        if (j > i) {
            float sj = ss[j], ej = ee[j];
            float inter = fmaxf(0.f, fminf(ei, ej) - fmaxf(si, sj));
            float uni = (ej - sj) + (ei - si) - inter;
            float iou = inter / fmaxf(uni, 1e-8f);
            if (iou > 0.7f) bits |= (1ull << jj);
        }
    }
    mask[(size_t)i * 16 + w] = bits;
}

// ---------------- NMS scan (readlane scalar-pipe) + partition + gather ----------------
__device__ __forceinline__ unsigned long long readlane64(unsigned long long v, int i) {
    unsigned int lo = (unsigned int)__builtin_amdgcn_readlane((int)(unsigned int)(v & 0xFFFFFFFFull), i);
    unsigned int hi = (unsigned int)__builtin_amdgcn_readlane((int)(unsigned int)(v >> 32), i);
    return ((unsigned long long)hi << 32) | (unsigned long long)lo;
}

__global__ __launch_bounds__(64) void nms_select_kernel(const unsigned long long* __restrict__ mask,
                                                        const int* __restrict__ topI,
                                                        const float* __restrict__ ss, const float* __restrict__ ee,
                                                        const float* __restrict__ cls2, const float* __restrict__ off2,
                                                        int* __restrict__ stA, int* __restrict__ enA,
                                                        float* __restrict__ out) {
    int lane = threadIdx.x;
    unsigned long long keepW[16];
#pragma unroll 1
    for (int b = 0; b < 16; b++) {
        unsigned long long accv = 0ull;
#pragma unroll 1
        for (int a = 0; a < b; a++) {
            unsigned long long m = mask[(size_t)(a * 64 + lane) * 16 + b];
            unsigned long long kb = (keepW[a] >> lane) & 1ull;
            accv |= m & (0ull - kb);
        }
#pragma unroll
        for (int sft = 1; sft < 64; sft <<= 1) accv |= __shfl_xor(accv, sft);
        unsigned long long diag = mask[(size_t)(b * 64 + lane) * 16 + b];
        unsigned long long rem = accv;
#pragma unroll
        for (int i = 0; i < 64; i++) {
            unsigned long long di = readlane64(diag, i);
            if (!((rem >> i) & 1ull)) rem |= di;
        }
        keepW[b] = ~rem;
    }
    int total = 0;
    int prefix[16];
#pragma unroll
    for (int b = 0; b < 16; b++) { prefix[b] = total; total += __popcll(keepW[b]); }
#pragma unroll 1
    for (int b = 0; b < 16; b++) {
        int tid = b * 64 + lane;
        unsigned long long keep64 = keepW[b];
        unsigned long long below = (lane == 0) ? 0ull : (keep64 << (64 - lane));
        int keptBefore = prefix[b] + __popcll(below);
        int kp = (int)((keep64 >> lane) & 1ull);
        int pos = kp ? keptBefore : (total + tid - keptBefore);
        if (pos < 128) {
            int orig = topI[tid];
            float ps = ss[tid], pe = ee[tid];
            out[pos * 2 + 0] = cls2[orig * 2 + 0];
            out[pos * 2 + 1] = cls2[orig * 2 + 1];
            out[256 + pos * 2 + 0] = off2[orig * 2 + 0];
            out[256 + pos * 2 + 1] = off2[orig * 2 + 1];
            float bc = (ps + pe) * 0.5f, bh = (pe - ps) * 0.5f;
            int st = (int)fminf(fmaxf(floorf(bc - bh), 0.f), 767.f);
            int en = (int)fminf(fmaxf(ceilf(bc + bh), 0.f), 767.f);
            if (en < st) en = st;
            stA[pos] = st;
            enA[pos] = en;
        }
    }
}

// ---------------- ROI max pool -> 898-row hi/lo slab [row c+1][2048] ----------------
__global__ __launch_bounds__(256) void roi_slab_kernel(const float* __restrict__ f,
                                                       const int* __restrict__ stA, const int* __restrict__ enA,
                                                       unsigned short* __restrict__ Xs) {
    int col = blockIdx.x;  // 0..895
    int n = col / 7, b = col - n * 7;
    int st = stA[n], en = enA[n];
    int ln = en - st + 1;
    int bs = st + (b * ln) / 7;
    int be = st + ((b + 1) * ln + 6) / 7 - 1;
    unsigned short* Xh = Xs;
    unsigned short* Xl = Xs + (size_t)898 * 2048;
    int tid = threadIdx.x;
#pragma unroll 1
    for (int j = 0; j < 8; j++) {
        int ci = tid + 256 * j;
        const float* row = f + (size_t)ci * 768;
        float m = row[bs];
        for (int t = bs + 1; t <= be; t++) m = fmaxf(m, row[t]);
        unsigned short h = f2b(m);
        float lo = m - bf(h);
        size_t o = (size_t)(col + 1) * 2048 + ci;
        Xh[o] = h;
        Xl[o] = f2b(lo);
    }
}

__global__ __launch_bounds__(256) void zrow_wc2_kernel(unsigned short* __restrict__ Xs) {
    int i = blockIdx.x * 256 + threadIdx.x;
    if (i < 2048) {
        Xs[i] = 0;
        Xs[(size_t)897 * 2048 + i] = 0;
        Xs[(size_t)898 * 2048 + i] = 0;
        Xs[(size_t)898 * 2048 + (size_t)897 * 2048 + i] = 0;
    }
}

__global__ __launch_bounds__(256) void zseg_kernel(uint4* __restrict__ p, int n16) {
    int i = blockIdx.x * 256 + threadIdx.x;
    uint4 z = {0, 0, 0, 0};
    if (i < n16) p[i] = z;
}

extern "C" void kernel_launch(void* const* d_in, const int* in_sizes, int n_in,
                              void* d_out, int out_size, void* d_ws, size_t ws_size,
                              hipStream_t stream) {
    const float* IN[39];
    for (int i = 0; i < 39; i++) IN[i] = (const float*)d_in[i];
    const float* feature = IN[0];
    const float *b1f = IN[1], *b2f = IN[2], *b3 = IN[3], *b4 = IN[4], *b5 = IN[5], *b6 = IN[6];
    const float *bc1 = IN[7], *bc2 = IN[8], *boxb = IN[9], *boxw = IN[10];
    const float *clsb = IN[11], *clsw = IN[12];
    const float *fc1b = IN[13], *fc1w = IN[14], *fc2b = IN[15], *fc2w = IN[16];
    const float *fc3b = IN[17], *fc3w = IN[18];
    const float *sp1b = IN[19], *sp1w = IN[20], *sp2b = IN[21], *sp2w = IN[22];
    const float *sp3b = IN[23], *sp3w = IN[24], *sp4b = IN[25], *sp4w = IN[26];
    const float *spcb = IN[27], *spcw = IN[28], *spsb = IN[29], *spsw = IN[30];
    const float *w1f = IN[31], *w2f = IN[32], *w3w = IN[33], *w4w = IN[34];
    const float *w5w = IN[35], *w6w = IN[36], *wc1 = IN[37], *wc2 = IN[38];
    float* out = (float*)d_out;

    char* base = (char*)d_ws;
    float* G    = (float*)base;   // conv phase ≤25.2 MB; tower phase 14.68 MB
    float* part = (float*)base;   // fc1 partials + heads partials (phase-local)
    unsigned short* WrSmall = (unsigned short*)(base + 14680064);  // conv-phase small repacks
    unsigned short* segSA = (unsigned short*)(base + 14680064);    // tower phase
    unsigned short* segSB = (unsigned short*)(base + 17055744);
    float* yA   = (float*)(base + 22020096);
    float* g1   = (float*)(base + 25690112);
    float* g2   = (float*)(base + 25952256);
    float* g3   = (float*)(base + 26083328);
    size_t off = 26148864;
    auto alloc = [&](size_t bytes) { void* p = base + off; off += (bytes + 63) & ~((size_t)63); return p; };
    unsigned short* Xt = (unsigned short*)alloc((size_t)898 * 2048 * 2 * 2);  // 898-slab fits
    float* fbuf = (float*)alloc((size_t)2048 * 768 * 4);
    unsigned short* WrWc2 = (unsigned short*)fbuf;                  // reused after roi_slab
    unsigned short* WrTower = (unsigned short*)Xt;                  // reused after wc2 conv
    float* hB   = (float*)alloc((size_t)512 * 768 * 4);
    float* clsS = (float*)alloc((size_t)20 * 768 * 4);
    float* segS = (float*)alloc((size_t)20 * 768 * 4);
    float* cls2 = (float*)alloc(7680 * 2 * 4);
    float* off2 = (float*)alloc(7680 * 2 * 4);
    float* scores = (float*)alloc(7680 * 4);
    float* sArr = (float*)alloc(7680 * 4);
    float* eArr = (float*)alloc(7680 * 4);
    float* ssS  = (float*)alloc(1024 * 4);
    float* eeS  = (float*)alloc(1024 * 4);
    unsigned long long* runs = (unsigned long long*)alloc((size_t)8192 * 8);
    unsigned long long* mask = (unsigned long long*)alloc((size_t)16384 * 8);
    int* topI = (int*)alloc(1024 * 4);
    int* stA = (int*)alloc(128 * 4);
    int* enA = (int*)alloc(128 * 4);

    // big-conv repack buffer (50.33 MB) — only if workspace allows
    size_t bigWrBytes = (size_t)2048 * 3 * 2 * 2048 * 2;
    unsigned short* WrBig = (unsigned short*)alloc(bigWrBytes);
    bool useBigWr = (off <= ws_size);

    dim3 blk(256);
    dim3 blk512(512);

    // ---- conv1: feature -> slab; W repack (if room) -> conv -> slab ----
    zeroXt_kernel<<<16, blk, 0, stream>>>(Xt, 2048);
    decomp_kernel<<<dim3(24, 64), blk, 0, stream>>>(feature, Xt, 2048);
    if (useBigWr) {
        repackW_kernel<<<49152, blk, 0, stream>>>(w1f, WrBig, 2048, 2048, 3);
        convmmW_kernel<3, 0><<<dim3(32, 6, 4), blk512, 0, stream>>>(WrBig, Xt, G, 2048, 2048, 4, 768, 770 * 2048);
    } else {
        convmm_kernel<<<dim3(32, 6, 4), blk512, 0, stream>>>(w1f, Xt, G, 2048, 2048, 4, 768, 770 * 2048);
    }
    finsum_x_kernel<<<dim3(32, 12), blk, 0, stream>>>(G, b1f, Xt, 2048, 4);
    // ---- conv2 ----
    if (useBigWr) {
        repackW_kernel<<<49152, blk, 0, stream>>>(w2f, WrBig, 2048, 2048, 3);
        convmmW_kernel<3, 0><<<dim3(32, 6, 4), blk512, 0, stream>>>(WrBig, Xt, G, 2048, 2048, 4, 768, 770 * 2048);
    } else {
        convmm_kernel<<<dim3(32, 6, 4), blk512, 0, stream>>>(w2f, Xt, G, 2048, 2048, 4, 768, 770 * 2048);
    }
    finsum_xf_kernel<<<dim3(32, 12), blk, 0, stream>>>(G, b2f, Xt, fbuf, 2048, 4);

    // ---- wc1 via repacked MFMA (TAPS=1 on conv2 slab) -> 512-slab ----
    repackW_kernel<<<4096, blk, 0, stream>>>(wc1, WrSmall, 512, 2048, 1);
    convmmW_kernel<1, 0><<<dim3(8, 6, 8), blk512, 0, stream>>>(WrSmall, Xt, G, 512, 2048, 8, 768, 770 * 2048);
    zeroXt_kernel<<<4, blk, 0, stream>>>(Xt, 512);
    finsum_x_kernel<<<dim3(8, 12), blk, 0, stream>>>(G, bc1, Xt, 512, 8);

    // ---- sp1..sp4 via repacked MFMA ----
    repackW_kernel<<<3072, blk, 0, stream>>>(sp1w, WrSmall, 512, 512, 3);
    convmmW_kernel<3, 0><<<dim3(8, 6, 8), blk512, 0, stream>>>(WrSmall, Xt, G, 512, 512, 8, 768, 770 * 512);
    finsum_x_kernel<<<dim3(8, 12), blk, 0, stream>>>(G, sp1b, Xt, 512, 8);
    repackW_kernel<<<3072, blk, 0, stream>>>(sp2w, WrSmall, 512, 512, 3);
    convmmW_kernel<3, 0><<<dim3(8, 6, 8), blk512, 0, stream>>>(WrSmall, Xt, G, 512, 512, 8, 768, 770 * 512);
    finsum_x_kernel<<<dim3(8, 12), blk, 0, stream>>>(G, sp2b, Xt, 512, 8);
    repackW_kernel<<<3072, blk, 0, stream>>>(sp3w, WrSmall, 512, 512, 3);
    convmmW_kernel<3, 0><<<dim3(8, 6, 8), blk512, 0, stream>>>(WrSmall, Xt, G, 512, 512, 8, 768, 770 * 512);
    finsum_x_kernel<<<dim3(8, 12), blk, 0, stream>>>(G, sp3b, Xt, 512, 8);
    repackW_kernel<<<3072, blk, 0, stream>>>(sp4w, WrSmall, 512, 512, 3);
    convmmW_kernel<3, 0><<<dim3(8, 6, 8), blk512, 0, stream>>>(WrSmall, Xt, G, 512, 512, 8, 768, 770 * 512);
    finsum_f_kernel<<<1536, blk, 0, stream>>>(G, sp4b, hB, 512, 8, 768, 1);  // relu

    // ---- heads (split-K S=8; partials in dead G region) ----
    gemm_kernel<0, 0><<<dim3(1, 12, 8), blk, 0, stream>>>(spcw, hB, spcb, part, 20, 512, 768, 768, 8, 0);
    finalize_kernel<<<60, blk, 0, stream>>>(part, clsS, spcb, 20, 20, 768, 8, 0);
    gemm_kernel<0, 0><<<dim3(1, 12, 8), blk, 0, stream>>>(spsw, hB, spsb, part, 20, 512, 768, 768, 8, 0);
    finalize_kernel<<<60, blk, 0, stream>>>(part, segS, spsb, 20, 20, 768, 8, 0);

    // ---- proposal decode / top-k / NMS ----
    proposal_kernel<<<30, blk, 0, stream>>>(clsS, segS, cls2, off2, scores, sArr, eArr);
    sortA_kernel<<<8, 1024, 0, stream>>>(scores, runs);
    sortB_kernel<<<1, 1024, 0, stream>>>(runs, sArr, eArr, topI, ssS, eeS);
    nms_mask_kernel<<<64, blk, 0, stream>>>(ssS, eeS, mask);
    nms_select_kernel<<<1, 64, 0, stream>>>(mask, topI, ssS, eeS, cls2, off2, stA, enA, out);

    // ---- ROI pool -> wc2 slab (Xt, 898 rows x 2048) ----
    zrow_wc2_kernel<<<8, blk, 0, stream>>>(Xt);
    roi_slab_kernel<<<896, blk, 0, stream>>>(fbuf, stA, enA, Xt);
    zseg_kernel<<<1160, blk, 0, stream>>>((uint4*)segSA, 296960);

    // ---- classifier tower via repacked MFMA ----
    repackW_kernel<<<4096, blk, 0, stream>>>(wc2, WrWc2, 512, 2048, 1);  // fbuf dead after roi
    convmmW_kernel<1, 0><<<dim3(8, 7, 8), blk512, 0, stream>>>(WrWc2, Xt, G, 512, 2048, 8, 896, 898 * 2048);
    finsum_seg_kernel<<<dim3(8, 14), blk, 0, stream>>>(G, bc2, segSA, 8, 0);
    repackW_kernel<<<3072, blk, 0, stream>>>(w3w, WrTower, 512, 512, 3);  // Xt dead after wc2 conv
    convmmW_kernel<3, 1><<<dim3(8, 7, 8), blk512, 0, stream>>>(WrTower, segSA, G, 512, 512, 8, 896, 1160 * 512);
    finsum_seg_kernel<<<dim3(8, 14), blk, 0, stream>>>(G, b3, segSB, 8, 0);
    repackW_kernel<<<3072, blk, 0, stream>>>(w4w, WrTower, 512, 512, 3);
    convmmW_kernel<3, 1><<<dim3(8, 7, 8), blk512, 0, stream>>>(WrTower, segSB, G, 512, 512, 8, 896, 1160 * 512);
    finsum_seg_kernel<<<dim3(8, 14), blk, 0, stream>>>(G, b4, segSA, 8, 1);  // relu
    repackW_kernel<<<3072, blk, 0, stream>>>(w5w, WrTower, 512, 512, 3);
    convmmW_kernel<3, 1><<<dim3(8, 7, 8), blk512, 0, stream>>>(WrTower, segSA, G, 512, 512, 8, 896, 1160 * 512);
    finsum_seg_kernel<<<dim3(8, 14), blk, 0, stream>>>(G, b5, segSB, 8, 0);
    repackW_kernel<<<3072, blk, 0, stream>>>(w6w, WrTower, 512, 512, 3);
    convmmW_kernel<3, 1><<<dim3(8, 7, 8), blk512, 0, stream>>>(WrTower, segSB, G, 512, 512, 8, 896, 1160 * 512);
    finsum_f_kernel<<<1792, blk, 0, stream>>>(G, b6, yA, 512, 8, 896, 1);  // relu -> fp32 [512][896]

    // ---- fc1 (relu), fc2, fc3, output heads (fp32) ----
    gemm_kernel<1, 0><<<dim3(8, 2, 28), blk, 0, stream>>>(fc1w, yA, fc1b, part, 512, 3584, 128, 128, 28, 0);
    finalize_kernel<<<256, blk, 0, stream>>>(part, g1, fc1b, 512, 512, 128, 28, 1);

    gemm_kernel<0, 0><<<dim3(4, 2, 4), blk, 0, stream>>>(fc2w, g1, fc2b, part, 256, 512, 128, 128, 4, 0);
    finalize_kernel<<<128, blk, 0, stream>>>(part, g2, fc2b, 256, 256, 128, 4, 0);
    gemm_kernel<0, 0><<<dim3(2, 2, 2), blk, 0, stream>>>(fc3w, g2, fc3b, part, 128, 256, 128, 128, 2, 0);
    finalize_kernel<<<64, blk, 0, stream>>>(part, g3, fc3b, 128, 128, 128, 2, 0);

    gemm_kernel<0, 1><<<dim3(1, 2, 1), blk, 0, stream>>>(clsw, g3, clsb, out, 21, 128, 128, 128, 1, 0);
    gemm_kernel<0, 2><<<dim3(1, 2, 1), blk, 0, stream>>>(boxw, g3, boxb, out, 40, 128, 128, 128, 1, 0);
}